// Round 9
// baseline (135.352 us; speedup 1.0000x reference)
//
#include <hip/hip_runtime.h>
#include <hip/hip_fp16.h>

#define HH 256
#define WW 704
#define DD 64
#define CC 3
#define BB 2
#define HWN (HH * WW)       // 180224

#define TY 8                // out-tile rows
#define TX 16               // out-tile cols
#define RY1 10              // q1 region rows (tile + 2*1 halo)
#define RX1 18              // q1 region cols
#define NP1 (RY1 * RX1)     // 180
#define NTX (WW / TX)       // 44
#define NTY (HH / TY)       // 32
#define NTILES (NTX * NTY)  // 1408 (divisible by 8 -> bijective XCD swizzle)

static constexpr float INV2Z2 = 1.0f / (2.0f * 1e-3f * 1e-3f);

// ---------------------------------------------------------------------------
// Affinity (r6 version, 1 px/thread, 1408x2 blocks — known-good occupancy):
// kaff[b,k,n] = ws * exp(-sum_c (uc-c)^2/(2 zeta^2)); zero-pad semantics.
// ---------------------------------------------------------------------------
__global__ __launch_bounds__(256) void affinity_kernel(
    const float* __restrict__ color, const float* __restrict__ wsp,
    float* __restrict__ kaff)
{
    int n = blockIdx.x * 256 + threadIdx.x;
    int b = blockIdx.y;
    int h = n / WW, w = n - h * WW;
    float wsv = wsp[0];

    const float* cb = color + (size_t)b * CC * HWN + n;
    float c0 = cb[0], c1 = cb[HWN], c2 = cb[2 * HWN];
    bool hm = h > 0, hp = h < HH - 1, wm = w > 0, wp = w < WW - 1;

    float* kb = kaff + (size_t)b * 9 * HWN + n;
#pragma unroll
    for (int dh = -1; dh <= 1; ++dh) {
#pragma unroll
        for (int dw = -1; dw <= 1; ++dw) {
            int k = (dh + 1) * 3 + (dw + 1);
            bool valid = (dh < 0 ? hm : (dh > 0 ? hp : true)) &&
                         (dw < 0 ? wm : (dw > 0 ? wp : true));
            int off = valid ? (dh * WW + dw) : 0;
            float u0 = valid ? cb[off] : 0.f;
            float u1 = valid ? cb[HWN + off] : 0.f;
            float u2 = valid ? cb[2 * HWN + off] : 0.f;
            float d0 = u0 - c0, d1 = u1 - c1, d2 = u2 - c2;
            float ss = d0 * d0 + d1 * d1 + d2 * d2;
            kb[(size_t)k * HWN] = wsv * __expf(-ss * INV2Z2);
        }
    }
}

// ---------------------------------------------------------------------------
// q0 = softmax(logits), computed ONCE per px (no halo duplication), stored
// px-major f16: q0g[(b*HWN + n)*32 + dword], 64 ch = 32 dwords = 128 B/px.
// Task = 1 px, 4 lanes x 16 ch (pxl = lane&15, cg = lane>>4).
// ---------------------------------------------------------------------------
__global__ __launch_bounds__(256) void q0softmax_kernel(
    const float* __restrict__ logits, unsigned* __restrict__ q0g)
{
    const int t = threadIdx.x, lane = t & 63, wv = t >> 6;
    const int pxl = lane & 15, cg = lane >> 4;
    const int n = blockIdx.x * 64 + wv * 16 + pxl;
    const int b = blockIdx.y;

    const float* lg = logits + ((size_t)b * DD + cg * 16) * HWN + n;
    float v[16];
    float s = 0.f;
#pragma unroll
    for (int i = 0; i < 16; ++i) {
        v[i] = __expf(lg[(size_t)i * HWN]);
        s += v[i];
    }
    s += __shfl_xor(s, 16);
    s += __shfl_xor(s, 32);
    float inv = 1.0f / s;

    __half2* qp = (__half2*)(q0g + ((size_t)b * HWN + n) * 32 + cg * 8);
    qp[0] = __floats2half2_rn(v[0]  * inv, v[1]  * inv);
    qp[1] = __floats2half2_rn(v[2]  * inv, v[3]  * inv);
    qp[2] = __floats2half2_rn(v[4]  * inv, v[5]  * inv);
    qp[3] = __floats2half2_rn(v[6]  * inv, v[7]  * inv);
    qp[4] = __floats2half2_rn(v[8]  * inv, v[9]  * inv);
    qp[5] = __floats2half2_rn(v[10] * inv, v[11] * inv);
    qp[6] = __floats2half2_rn(v[12] * inv, v[13] * inv);
    qp[7] = __floats2half2_rn(v[14] * inv, v[15] * inv);
}

// ---------------------------------------------------------------------------
// LDS q1 layout: px-major, 32 dwords/px, XOR swizzle dw(p,q)=p*32+(q^((p&7)<<2))
// ---------------------------------------------------------------------------
__device__ __forceinline__ void acc_tap(const unsigned* q, int p0, int cg,
                                        __half2 kh, __half2* tv2) {
    int ia = p0 * 32 + ((cg * 8) ^ ((p0 & 7) << 2));
    int ib = ia ^ 4;
    const __half2* qa = (const __half2*)&q[ia];
    const __half2* qb = (const __half2*)&q[ib];
    tv2[0] = __hfma2(kh, qa[0], tv2[0]);
    tv2[1] = __hfma2(kh, qa[1], tv2[1]);
    tv2[2] = __hfma2(kh, qa[2], tv2[2]);
    tv2[3] = __hfma2(kh, qa[3], tv2[3]);
    tv2[4] = __hfma2(kh, qb[0], tv2[4]);
    tv2[5] = __hfma2(kh, qb[1], tv2[5]);
    tv2[6] = __hfma2(kh, qb[2], tv2[6]);
    tv2[7] = __hfma2(kh, qb[3], tv2[7]);
}

// global (unswizzled) tap: qp points at this px's dwords for this cg
__device__ __forceinline__ void acc_tap_g(const unsigned* qp, __half2 kh,
                                          __half2* tv2) {
    const __half2* qa = (const __half2*)qp;
    const __half2* qb = (const __half2*)(qp + 4);
    tv2[0] = __hfma2(kh, qa[0], tv2[0]);
    tv2[1] = __hfma2(kh, qa[1], tv2[1]);
    tv2[2] = __hfma2(kh, qa[2], tv2[2]);
    tv2[3] = __hfma2(kh, qa[3], tv2[3]);
    tv2[4] = __hfma2(kh, qb[0], tv2[4]);
    tv2[5] = __hfma2(kh, qb[1], tv2[5]);
    tv2[6] = __hfma2(kh, qb[2], tv2[6]);
    tv2[7] = __hfma2(kh, qb[3], tv2[7]);
}

__device__ __forceinline__ void st_px(unsigned* q, int p, int cg,
                                      const float* u, float scale) {
    int ia = p * 32 + ((cg * 8) ^ ((p & 7) << 2));
    int ib = ia ^ 4;
    __half2* qa = (__half2*)&q[ia];
    __half2* qb = (__half2*)&q[ib];
    qa[0] = __floats2half2_rn(u[0]  * scale, u[1]  * scale);
    qa[1] = __floats2half2_rn(u[2]  * scale, u[3]  * scale);
    qa[2] = __floats2half2_rn(u[4]  * scale, u[5]  * scale);
    qa[3] = __floats2half2_rn(u[6]  * scale, u[7]  * scale);
    qb[0] = __floats2half2_rn(u[8]  * scale, u[9]  * scale);
    qb[1] = __floats2half2_rn(u[10] * scale, u[11] * scale);
    qb[2] = __floats2half2_rn(u[12] * scale, u[13] * scale);
    qb[3] = __floats2half2_rn(u[14] * scale, u[15] * scale);
}

__device__ __forceinline__ void scan4(float Aloc, float Bloc, int pxl, int cg,
                                      float& Ar, float& Br, float& T, float& E) {
    float A0 = __shfl(Aloc, pxl),      A1 = __shfl(Aloc, pxl + 16),
          A2 = __shfl(Aloc, pxl + 32), A3 = __shfl(Aloc, pxl + 48);
    float B0 = __shfl(Bloc, pxl),      B1 = __shfl(Bloc, pxl + 16),
          B2 = __shfl(Bloc, pxl + 32), B3 = __shfl(Bloc, pxl + 48);
    T = A0 + A1 + A2 + A3;  E = B0 + B1 + B2 + B3;
    Ar = 0.f; Br = 0.f;
    if (cg > 0) { Ar += A0; Br += B0; }
    if (cg > 1) { Ar += A1; Br += B1; }
    if (cg > 2) { Ar += A2; Br += B2; }
}

__device__ __forceinline__ float finish_px(float* tv, const float* lgv,
                                           int pxl, int cg) {
    float Aloc = 0.f, Bloc = 0.f;
#pragma unroll
    for (int i = 0; i < 16; ++i) {
        float e = (float)(cg * 16 + i);
        Aloc += tv[i]; Bloc += e * tv[i];
    }
    float Ar, Br, T, E;
    scan4(Aloc, Bloc, pxl, cg, Ar, Br, T, E);
    float s = 0.f;
#pragma unroll
    for (int i = 0; i < 16; ++i) {
        float e = (float)(cg * 16 + i);
        Ar += tv[i]; Br += e * tv[i];
        float v = lgv[i] - (2.f * (e * Ar - Br) + E - e * T);
        tv[i] = __expf(v); s += tv[i];
    }
    s += __shfl_xor(s, 16);
    s += __shfl_xor(s, 32);
    return 1.f / s;
}

__device__ __forceinline__ void load_k(const float* kfb, int n, int gy, int gx,
                                       float* k) {
#pragma unroll
    for (int j = 0; j < 9; ++j) k[j] = kfb[(size_t)j * HWN + n];
    if (gy <= 0)      { k[0] = k[1] = k[2] = 0.f; }
    if (gy >= HH - 1) { k[6] = k[7] = k[8] = 0.f; }
    if (gx <= 0)      { k[0] = k[3] = k[6] = 0.f; }
    if (gx >= WW - 1) { k[2] = k[5] = k[8] = 0.f; }
}

// 9-tap LDS stencil -> tv[16] f32 (for P2)
__device__ __forceinline__ void stencil9(const unsigned* qs, int rowstride,
                                         int py, int px, int cg,
                                         const float* k, float* tv) {
    __half2 tv2[8];
#pragma unroll
    for (int j = 0; j < 8; ++j) tv2[j] = __float2half2_rn(0.f);
    int base = (py + 1) * rowstride + (px + 1);
#pragma unroll
    for (int tap = 0; tap < 9; ++tap) {
        int dy = tap / 3 - 1, dx = tap - (tap / 3) * 3 - 1;
        acc_tap(qs, base + dy * rowstride + dx, cg, __float2half2_rn(k[tap]), tv2);
    }
#pragma unroll
    for (int j = 0; j < 8; ++j) {
        float2 f = __half22float2(tv2[j]);
        tv[2 * j] = f.x; tv[2 * j + 1] = f.y;
    }
}

// ---------------------------------------------------------------------------
// Fused P1+P2 per 8x16 out-tile (task = 1 px, 4 lanes x 16 ch):
//   P1: q1 = iter(q0g) on 10x18 -> LDS f16 (q0 halo read from global; the
//       block's 23 KB q0 region is L1/L2-resident across the 9 taps)
//   P2: q2 = iter(q1) on 8x16 -> global
// Only q1s in LDS (23 KB) -> 5-6 blocks/CU.
// ---------------------------------------------------------------------------
__global__ __launch_bounds__(256) void fused_crf_kernel(
    const float* __restrict__ logits, const float* __restrict__ kaff,
    const unsigned* __restrict__ q0g, float* __restrict__ qout)
{
    __shared__ unsigned q1s[NP1 * 32];   // 23,040 B

    const int t = threadIdx.x;
    const int lane = t & 63;
    const int wv = t >> 6;          // 0..3
    const int pxl = lane & 15;
    const int cg = lane >> 4;       // channels [16cg, 16cg+16)
    const int b = blockIdx.y;

    const int bid = blockIdx.x;     // XCD swizzle (1408 % 8 == 0 -> bijective)
    const int pb = (bid & 7) * (NTILES / 8) + (bid >> 3);
    const int tyr = pb / NTX, txc = pb - tyr * NTX;
    const int y0 = tyr * TY, x0 = txc * TX;

    const float* lgb = logits + ((size_t)b * DD + cg * 16) * HWN;
    const float* kfb = kaff + (size_t)b * 9 * HWN;
    const unsigned* q0b = q0g + (size_t)b * HWN * 32;

    // ---------------- P1: q1 = iter(q0g) on 10x18 ----------------
    for (int r = 0; r < 3; ++r) {
        int id = r * 64 + wv * 16 + pxl;
        if (id < NP1) {
            int py = id / RX1, px = id - py * RX1;
            int gy = y0 - 1 + py, gx = x0 - 1 + px;   // may be out of image
            int cy = min(max(gy, 0), HH - 1), cx = min(max(gx, 0), WW - 1);
            int n = cy * WW + cx;

            float k[9];
            load_k(kfb, n, gy, gx, k);
            const float* lgn = lgb + n;
            float lgv[16];
#pragma unroll
            for (int i = 0; i < 16; ++i) lgv[i] = lgn[(size_t)i * HWN];

            int rU = min(max(gy - 1, 0), HH - 1);
            int rD = min(max(gy + 1, 0), HH - 1);
            int dl = (cx > 0) ? -32 : 0;
            int dr = (cx < WW - 1) ? 32 : 0;
            const unsigned* pU = q0b + ((size_t)rU * WW + cx) * 32 + cg * 8;
            const unsigned* pM = q0b + ((size_t)cy * WW + cx) * 32 + cg * 8;
            const unsigned* pD = q0b + ((size_t)rD * WW + cx) * 32 + cg * 8;

            __half2 tv2[8];
#pragma unroll
            for (int j = 0; j < 8; ++j) tv2[j] = __float2half2_rn(0.f);
            acc_tap_g(pU + dl, __float2half2_rn(k[0]), tv2);
            acc_tap_g(pU,      __float2half2_rn(k[1]), tv2);
            acc_tap_g(pU + dr, __float2half2_rn(k[2]), tv2);
            acc_tap_g(pM + dl, __float2half2_rn(k[3]), tv2);
            acc_tap_g(pM,      __float2half2_rn(k[4]), tv2);
            acc_tap_g(pM + dr, __float2half2_rn(k[5]), tv2);
            acc_tap_g(pD + dl, __float2half2_rn(k[6]), tv2);
            acc_tap_g(pD,      __float2half2_rn(k[7]), tv2);
            acc_tap_g(pD + dr, __float2half2_rn(k[8]), tv2);

            float tv[16];
#pragma unroll
            for (int j = 0; j < 8; ++j) {
                float2 f = __half22float2(tv2[j]);
                tv[2 * j] = f.x; tv[2 * j + 1] = f.y;
            }
            float inv = finish_px(tv, lgv, pxl, cg);
            st_px(q1s, id, cg, tv, inv);
        }
    }
    __syncthreads();

    // ---------------- P2: q2 = iter(q1) -> global, 8x16 ----------------
    for (int r = 0; r < 2; ++r) {
        int id = r * 64 + wv * 16 + pxl;     // 0..127, all valid
        int py = id >> 4, px = id & 15;
        int gy = y0 + py, gx = x0 + px;      // always in image
        int n = gy * WW + gx;

        float k[9];
        load_k(kfb, n, gy, gx, k);
        const float* lgn = lgb + n;
        float lgv[16];
#pragma unroll
        for (int i = 0; i < 16; ++i) lgv[i] = lgn[(size_t)i * HWN];

        float tv[16];
        stencil9(q1s, RX1, py, px, cg, k, tv);
        float inv = finish_px(tv, lgv, pxl, cg);

        float* qo = qout + ((size_t)b * DD + cg * 16) * HWN + n;
#pragma unroll
        for (int i = 0; i < 16; ++i) qo[(size_t)i * HWN] = tv[i] * inv;
    }
}

// ---------------------------------------------------------------------------
extern "C" void kernel_launch(void* const* d_in, const int* in_sizes, int n_in,
                              void* d_out, int out_size, void* d_ws, size_t ws_size,
                              hipStream_t stream) {
    const float* color  = (const float*)d_in[0];
    // d_in[1] = feats: unused by the forward pass
    const float* logits = (const float*)d_in[2];
    const float* wsp    = (const float*)d_in[3];

    float* q_out = (float*)d_out;
    float* kaff  = (float*)d_ws;                              // [B,9,HW] f32, 13 MB
    unsigned* q0g = (unsigned*)((float*)d_ws + (size_t)BB * 9 * HWN); // [B,HW,32] f16x2, 46 MB

    dim3 gridA(HWN / 256, BB);
    affinity_kernel<<<gridA, 256, 0, stream>>>(color, wsp, kaff);

    dim3 gridQ(HWN / 64, BB);
    q0softmax_kernel<<<gridQ, 256, 0, stream>>>(logits, q0g);

    dim3 gridF(NTILES, BB);               // 1408 tiles x 2 batches
    fused_crf_kernel<<<gridF, 256, 0, stream>>>(logits, kaff, q0g, q_out);
}

// Round 10
// 122.089 us; speedup vs baseline: 1.1086x; 1.1086x over previous
//
#include <hip/hip_runtime.h>
#include <hip/hip_fp16.h>

#define HH 256
#define WW 704
#define DD 64
#define CC 3
#define BB 2
#define HWN (HH * WW)       // 180224

#define TY 8                // out-tile rows
#define TX 8                // out-tile cols
#define RY0 12              // q0 region rows (tile + 2*2 halo)
#define RX0 12              // q0 region cols
#define NP0 (RY0 * RX0)     // 144
#define RY1 10              // q1 region rows (tile + 2*1 halo)
#define RX1 10              // q1 region cols
#define NP1 (RY1 * RX1)     // 100
#define NTX (WW / TX)       // 88
#define NTY (HH / TY)       // 32
#define NTILES (NTX * NTY)  // 2816 (divisible by 8 -> bijective XCD swizzle)

static constexpr float INV2Z2 = 1.0f / (2.0f * 1e-3f * 1e-3f);

// ---------------------------------------------------------------------------
// Affinity (r6 version, 1 px/thread — known-good occupancy):
// kaff[b,k,n] = ws * exp(-sum_c (uc-c)^2/(2 zeta^2)); zero-pad semantics.
// ---------------------------------------------------------------------------
__global__ __launch_bounds__(256) void affinity_kernel(
    const float* __restrict__ color, const float* __restrict__ wsp,
    float* __restrict__ kaff)
{
    int n = blockIdx.x * 256 + threadIdx.x;
    int b = blockIdx.y;
    int h = n / WW, w = n - h * WW;
    float wsv = wsp[0];

    const float* cb = color + (size_t)b * CC * HWN + n;
    float c0 = cb[0], c1 = cb[HWN], c2 = cb[2 * HWN];
    bool hm = h > 0, hp = h < HH - 1, wm = w > 0, wp = w < WW - 1;

    float* kb = kaff + (size_t)b * 9 * HWN + n;
#pragma unroll
    for (int dh = -1; dh <= 1; ++dh) {
#pragma unroll
        for (int dw = -1; dw <= 1; ++dw) {
            int k = (dh + 1) * 3 + (dw + 1);
            bool valid = (dh < 0 ? hm : (dh > 0 ? hp : true)) &&
                         (dw < 0 ? wm : (dw > 0 ? wp : true));
            int off = valid ? (dh * WW + dw) : 0;
            float u0 = valid ? cb[off] : 0.f;
            float u1 = valid ? cb[HWN + off] : 0.f;
            float u2 = valid ? cb[2 * HWN + off] : 0.f;
            float d0 = u0 - c0, d1 = u1 - c1, d2 = u2 - c2;
            float ss = d0 * d0 + d1 * d1 + d2 * d2;
            kb[(size_t)k * HWN] = wsv * __expf(-ss * INV2Z2);
        }
    }
}

// ---------------------------------------------------------------------------
// LDS layout: px-major, 32 dwords (64 f16 ch) per px, XOR swizzle on dword
// index: dw(p,q) = p*32 + (q ^ ((p&7)<<2)). Same permutation on store and
// load -> correctness independent of the mixing.
// ---------------------------------------------------------------------------
__device__ __forceinline__ void acc_tap(const unsigned* q, int p0, int cg,
                                        __half2 kh, __half2* tv2) {
    int ia = p0 * 32 + ((cg * 8) ^ ((p0 & 7) << 2));
    int ib = ia ^ 4;
    const __half2* qa = (const __half2*)&q[ia];
    const __half2* qb = (const __half2*)&q[ib];
    tv2[0] = __hfma2(kh, qa[0], tv2[0]);
    tv2[1] = __hfma2(kh, qa[1], tv2[1]);
    tv2[2] = __hfma2(kh, qa[2], tv2[2]);
    tv2[3] = __hfma2(kh, qa[3], tv2[3]);
    tv2[4] = __hfma2(kh, qb[0], tv2[4]);
    tv2[5] = __hfma2(kh, qb[1], tv2[5]);
    tv2[6] = __hfma2(kh, qb[2], tv2[6]);
    tv2[7] = __hfma2(kh, qb[3], tv2[7]);
}

__device__ __forceinline__ void st_px(unsigned* q, int p, int cg,
                                      const float* u, float scale) {
    int ia = p * 32 + ((cg * 8) ^ ((p & 7) << 2));
    int ib = ia ^ 4;
    __half2* qa = (__half2*)&q[ia];
    __half2* qb = (__half2*)&q[ib];
    qa[0] = __floats2half2_rn(u[0]  * scale, u[1]  * scale);
    qa[1] = __floats2half2_rn(u[2]  * scale, u[3]  * scale);
    qa[2] = __floats2half2_rn(u[4]  * scale, u[5]  * scale);
    qa[3] = __floats2half2_rn(u[6]  * scale, u[7]  * scale);
    qb[0] = __floats2half2_rn(u[8]  * scale, u[9]  * scale);
    qb[1] = __floats2half2_rn(u[10] * scale, u[11] * scale);
    qb[2] = __floats2half2_rn(u[12] * scale, u[13] * scale);
    qb[3] = __floats2half2_rn(u[14] * scale, u[15] * scale);
}

__device__ __forceinline__ void scan4(float Aloc, float Bloc, int pxl, int cg,
                                      float& Ar, float& Br, float& T, float& E) {
    float A0 = __shfl(Aloc, pxl),      A1 = __shfl(Aloc, pxl + 16),
          A2 = __shfl(Aloc, pxl + 32), A3 = __shfl(Aloc, pxl + 48);
    float B0 = __shfl(Bloc, pxl),      B1 = __shfl(Bloc, pxl + 16),
          B2 = __shfl(Bloc, pxl + 32), B3 = __shfl(Bloc, pxl + 48);
    T = A0 + A1 + A2 + A3;  E = B0 + B1 + B2 + B3;
    Ar = 0.f; Br = 0.f;
    if (cg > 0) { Ar += A0; Br += B0; }
    if (cg > 1) { Ar += A1; Br += B1; }
    if (cg > 2) { Ar += A2; Br += B2; }
}

__device__ __forceinline__ float finish_px(float* tv, const float* lgv,
                                           int pxl, int cg) {
    float Aloc = 0.f, Bloc = 0.f;
#pragma unroll
    for (int i = 0; i < 16; ++i) {
        float e = (float)(cg * 16 + i);
        Aloc += tv[i]; Bloc += e * tv[i];
    }
    float Ar, Br, T, E;
    scan4(Aloc, Bloc, pxl, cg, Ar, Br, T, E);
    float s = 0.f;
#pragma unroll
    for (int i = 0; i < 16; ++i) {
        float e = (float)(cg * 16 + i);
        Ar += tv[i]; Br += e * tv[i];
        float v = lgv[i] - (2.f * (e * Ar - Br) + E - e * T);
        tv[i] = __expf(v); s += tv[i];
    }
    s += __shfl_xor(s, 16);
    s += __shfl_xor(s, 32);
    return 1.f / s;
}

__device__ __forceinline__ void load_k(const float* kfb, int n, int gy, int gx,
                                       float* k) {
#pragma unroll
    for (int j = 0; j < 9; ++j) k[j] = kfb[(size_t)j * HWN + n];
    if (gy <= 0)      { k[0] = k[1] = k[2] = 0.f; }
    if (gy >= HH - 1) { k[6] = k[7] = k[8] = 0.f; }
    if (gx <= 0)      { k[0] = k[3] = k[6] = 0.f; }
    if (gx >= WW - 1) { k[2] = k[5] = k[8] = 0.f; }
}

// 9-tap stencil from an LDS q-region into tv[16] (f32), via packed f16 FMA
__device__ __forceinline__ void stencil9(const unsigned* qs, int rowstride,
                                         int py, int px, int cg,
                                         const float* k, float* tv) {
    __half2 tv2[8];
#pragma unroll
    for (int j = 0; j < 8; ++j) tv2[j] = __float2half2_rn(0.f);
    int base = (py + 1) * rowstride + (px + 1);
#pragma unroll
    for (int tap = 0; tap < 9; ++tap) {
        int dy = tap / 3 - 1, dx = tap - (tap / 3) * 3 - 1;
        acc_tap(qs, base + dy * rowstride + dx, cg, __float2half2_rn(k[tap]), tv2);
    }
#pragma unroll
    for (int j = 0; j < 8; ++j) {
        float2 f = __half22float2(tv2[j]);
        tv[2 * j] = f.x; tv[2 * j + 1] = f.y;
    }
}

// ---------------------------------------------------------------------------
// Fused CRF per 8x8 out-tile (task = 1 px, 4 lanes x 16 ch):
//   P0: q0 = softmax(logits) on 12x12 -> LDS f16
//   P1: q1 = iter(q0) on 10x10 -> LDS f16
//   P2: q2 = iter(q1) on 8x8 -> global
// LDS 31.2 KB -> 5 blocks/CU (20 waves) for latency hiding.
// ---------------------------------------------------------------------------
__global__ __launch_bounds__(256) void fused_crf_kernel(
    const float* __restrict__ logits, const float* __restrict__ kaff,
    float* __restrict__ qout)
{
    __shared__ unsigned q0s[NP0 * 32];   // 18,432 B
    __shared__ unsigned q1s[NP1 * 32];   // 12,800 B

    const int t = threadIdx.x;
    const int lane = t & 63;
    const int wv = t >> 6;          // 0..3
    const int pxl = lane & 15;
    const int cg = lane >> 4;       // channels [16cg, 16cg+16)
    const int b = blockIdx.y;

    const int bid = blockIdx.x;     // XCD swizzle (2816 % 8 == 0 -> bijective)
    const int pb = (bid & 7) * (NTILES / 8) + (bid >> 3);
    const int tyr = pb / NTX, txc = pb - tyr * NTX;
    const int y0 = tyr * TY, x0 = txc * TX;

    const float* lgb = logits + ((size_t)b * DD + cg * 16) * HWN;
    const float* kfb = kaff + (size_t)b * 9 * HWN;

    // ---------------- P0: q0 = softmax(logits) on 12x12 ----------------
    for (int r = 0; r < 3; ++r) {
        int id = r * 64 + wv * 16 + pxl;
        if (id < NP0) {
            int py = id / RX0, px = id - py * RX0;
            int gy = min(max(y0 - 2 + py, 0), HH - 1);
            int gx = min(max(x0 - 2 + px, 0), WW - 1);
            const float* lg = lgb + gy * WW + gx;
            float v[16];
            float s = 0.f;
#pragma unroll
            for (int i = 0; i < 16; ++i) {
                v[i] = __expf(lg[(size_t)i * HWN]);
                s += v[i];
            }
            s += __shfl_xor(s, 16);
            s += __shfl_xor(s, 32);
            st_px(q0s, id, cg, v, 1.0f / s);
        }
    }
    __syncthreads();

    // ---------------- P1: q1 = iter(q0) on 10x10 ----------------
    for (int r = 0; r < 2; ++r) {
        int id = r * 64 + wv * 16 + pxl;
        if (id < NP1) {
            int py = id / RX1, px = id - py * RX1;
            int gy = y0 - 1 + py, gx = x0 - 1 + px;   // may be out of image
            int cy = min(max(gy, 0), HH - 1), cx = min(max(gx, 0), WW - 1);
            int n = cy * WW + cx;

            float k[9];
            load_k(kfb, n, gy, gx, k);
            const float* lgn = lgb + n;
            float lgv[16];
#pragma unroll
            for (int i = 0; i < 16; ++i) lgv[i] = lgn[(size_t)i * HWN];

            float tv[16];
            stencil9(q0s, RX0, py, px, cg, k, tv);
            float inv = finish_px(tv, lgv, pxl, cg);
            st_px(q1s, id, cg, tv, inv);
        }
    }
    __syncthreads();

    // ---------------- P2: q2 = iter(q1) -> global, 8x8 ----------------
    {
        int id = wv * 16 + pxl;              // 0..63, all valid
        int py = id >> 3, px = id & 7;
        int gy = y0 + py, gx = x0 + px;      // always in image
        int n = gy * WW + gx;

        float k[9];
        load_k(kfb, n, gy, gx, k);
        const float* lgn = lgb + n;
        float lgv[16];
#pragma unroll
        for (int i = 0; i < 16; ++i) lgv[i] = lgn[(size_t)i * HWN];

        float tv[16];
        stencil9(q1s, RX1, py, px, cg, k, tv);
        float inv = finish_px(tv, lgv, pxl, cg);

        float* qo = qout + ((size_t)b * DD + cg * 16) * HWN + n;
#pragma unroll
        for (int i = 0; i < 16; ++i) qo[(size_t)i * HWN] = tv[i] * inv;
    }
}

// ---------------------------------------------------------------------------
extern "C" void kernel_launch(void* const* d_in, const int* in_sizes, int n_in,
                              void* d_out, int out_size, void* d_ws, size_t ws_size,
                              hipStream_t stream) {
    const float* color  = (const float*)d_in[0];
    // d_in[1] = feats: unused by the forward pass
    const float* logits = (const float*)d_in[2];
    const float* wsp    = (const float*)d_in[3];

    float* q_out = (float*)d_out;
    float* kaff  = (float*)d_ws;          // [B,9,HW] f32, 13 MB

    dim3 gridA(HWN / 256, BB);
    affinity_kernel<<<gridA, 256, 0, stream>>>(color, wsp, kaff);

    dim3 gridF(NTILES, BB);               // 2816 tiles x 2 batches
    fused_crf_kernel<<<gridF, 256, 0, stream>>>(logits, kaff, q_out);
}